// Round 8
// baseline (357.456 us; speedup 1.0000x reference)
//
#include <hip/hip_runtime.h>

typedef __bf16 bf16x8 __attribute__((ext_vector_type(8)));
typedef float  floatx4 __attribute__((ext_vector_type(4)));

constexpr int B_    = 2048;
constexpr int NIN   = 256;
constexpr int H_    = 128;
constexpr int RANK_ = 8;
constexpr float EPS_ = 1e-5f;

// ---------------------------------------------------------------------------
// HEAD: zero stats; in_proj (2 rows per block, all 1024 blocks); pconv with
// LDS transpose (1 p-unit per block) -> coalesced global IO. Grid 1024 x 256.
__global__ __launch_bounds__(256)
void k_head(const float* __restrict__ X,
            const float* __restrict__ W1, const float* __restrict__ b1,
            const float* __restrict__ W2, const float* __restrict__ b2,
            const float* __restrict__ P,
            float* __restrict__ Z, float* __restrict__ R2, __bf16* __restrict__ Zbf,
            __bf16* __restrict__ Pperm, float* __restrict__ stats /* 9*256 */) {
    __shared__ __bf16 sT[128 * 40];          // 10240 B; also reused as fp32 sx[512]
    float* sx = (float*)sT;
    const int bx = blockIdx.x, t = threadIdx.x;

    if (bx < RANK_ + 1) stats[bx * 256 + t] = 0.f;

    {   // in_proj rows bx*2, bx*2+1
        const int row0 = bx * 2;
        sx[t]       = X[(size_t)row0       * NIN + t];
        sx[256 + t] = X[(size_t)(row0 + 1) * NIN + t];
        __syncthreads();
        const int col = t & 127, half = t >> 7;
        float s1 = 0.f, s2 = 0.f;
        const float* sxh = sx + half * 256;
#pragma unroll 8
        for (int i = 0; i < NIN; ++i) {
            s1 = fmaf(sxh[i], W1[i * H_ + col], s1);
            s2 = fmaf(sxh[i], W2[i * H_ + col], s2);
        }
        const int b = row0 + half;
        const float z = fmaxf(s1 + b1[col], 0.f);
        const float r = fmaxf(s2 + b2[col], 0.f);
        Z[(size_t)b * H_ + col]   = z;
        Zbf[(size_t)b * H_ + col] = (__bf16)z;
        R2[(size_t)b * H_ + col]  = r;
        __syncthreads();
    }
    {   // pconv: unit = bx (8 ranks x 128 p). LDS-transposed, coalesced IO.
        const int pr = bx >> 7, p = bx & 127;
        const float4* Pp4 = (const float4*)(P + ((size_t)pr * H_ + p) * (H_ * H_));
        __bf16* dp = Pperm + ((size_t)pr * H_ + p) * (H_ * H_);
        const int L = t & 63, quad = L >> 4, lo = L & 15, c0 = t >> 6;
#pragma unroll
        for (int s = 0; s < 4; ++s) {
#pragma unroll
            for (int i = 0; i < 4; ++i) {    // read 32 q-rows, contiguous float4
                const int idx = i * 256 + t;
                const int q = idx >> 5, k4 = idx & 31;
                const float4 v = Pp4[(size_t)(s * 32 + q) * 32 + k4];
                __bf16* d = sT + (size_t)(k4 * 4) * 40 + q;
                d[0]   = (__bf16)v.x;
                d[40]  = (__bf16)v.y;
                d[80]  = (__bf16)v.z;
                d[120] = (__bf16)v.w;
            }
            __syncthreads();
#pragma unroll
            for (int cc = 0; cc < 2; ++cc) { // emit frag-ordered, contiguous 16B
                const int c = c0 + 4 * cc;
                const bf16x8 v = *(const bf16x8*)&sT[(c * 16 + lo) * 40 + quad * 8];
                *(bf16x8*)(dp + (((size_t)(s * 8 + c)) * 64 + L) * 8) = v;
            }
            __syncthreads();
        }
    }
}

// ---------------------------------------------------------------------------
// RANK r: T_r = sum_p BNprev(prevT)[:,p] * (Zbf @ P_r[p]); stats_r.
// Grid (8 kg, 32 m) -> XCD = kg (L2-local 512KB B slice). Block 1024 thr
// (16 waves = 4 row-groups x 4 p-quarters), 4 waves/SIMD. B double-buffered.
__global__ __launch_bounds__(1024, 4)
void k_rank(const __bf16* __restrict__ Pr, const __bf16* __restrict__ Zbf,
            const float* __restrict__ prevT, const float* __restrict__ prevStats,
            const float* __restrict__ gz, const float* __restrict__ bz,
            float* __restrict__ T, float* __restrict__ stats, const int first) {
    __shared__ float smem[8960];     // sZin[128][68] | reduce[4096]+cs[32] ; sAl/sBe tail
    const int kg = blockIdx.x, mblk = blockIdx.y, b0 = mblk * 64;
    const int t = threadIdx.x;
    const int w = t >> 6, L = t & 63, quad = L >> 4, lo = L & 15;
    const int wr = w >> 2, wp = w & 3;

    float* sAl = smem + 8704; float* sBe = smem + 8832;
    if (t < 128) {
        if (first) { sAl[t] = 1.f; sBe[t] = 0.f; }
        else {
            const float s1 = prevStats[t], s2 = prevStats[128 + t];
            const float mm = s1 * (1.f / B_);
            const float var = s2 * (1.f / B_) - mm * mm;
            const float a = rsqrtf(var + EPS_) * gz[t];
            sAl[t] = a; sBe[t] = bz[t] - mm * a;
        }
    }
    // A-frags: 16 rows per wave (row-group wr), rank-invariant
    bf16x8 A[4];
#pragma unroll
    for (int ks = 0; ks < 4; ++ks)
        A[ks] = *(const bf16x8*)(Zbf + (size_t)(b0 + wr * 16 + lo) * H_ + ks * 32 + quad * 8);
    __syncthreads();
    {   // stage normalized Zin -> sZin[p][row], 64 rows
        const int sp = t & 127, rr = t >> 7;
        const float a = sAl[sp], be = sBe[sp];
#pragma unroll
        for (int i = 0; i < 8; ++i) {
            const int row = rr + 8 * i;
            smem[sp * 68 + row] = fmaf(prevT[(size_t)(b0 + row) * H_ + sp], a, be);
        }
    }
    __syncthreads();

    floatx4 acc = (floatx4){0.f, 0.f, 0.f, 0.f};
    const bf16x8* Pb = (const bf16x8*)Pr;
    bf16x8 Bf[4], Bn[4];
#pragma unroll
    for (int s = 0; s < 4; ++s)
        Bf[s] = Pb[((size_t)((wp * 4 + s) * 8 + kg)) * 64 + L];
#pragma unroll 2
    for (int pp = 0; pp < 32; ++pp) {
        const int p = pp * 4 + wp;
        if (pp < 31) {
            const int pn = p + 4;
#pragma unroll
            for (int s = 0; s < 4; ++s)
                Bn[s] = Pb[((size_t)((pn * 4 + s) * 8 + kg)) * 64 + L];
        }
        floatx4 S = (floatx4){0.f, 0.f, 0.f, 0.f};
#pragma unroll
        for (int ks = 0; ks < 4; ++ks)
            S = __builtin_amdgcn_mfma_f32_16x16x32_bf16(A[ks], Bf[ks], S, 0, 0, 0);
        const floatx4 zi = *(const floatx4*)&smem[p * 68 + wr * 16 + quad * 4];
        acc += zi * S;
#pragma unroll
        for (int s = 0; s < 4; ++s) Bf[s] = Bn[s];
    }
    __syncthreads();                 // sZin dead; reuse for cross-wave p-reduce
#pragma unroll
    for (int i = 0; i < 4; ++i)
        smem[((wr * 4 + wp) * 4 + i) * 64 + L] = acc[i];
    if (t < 32) smem[4096 + t] = 0.f;
    __syncthreads();

    // one output element per thread
    const int g = t >> 6, L2 = t & 63;
    const int wr2 = g >> 2, i2 = g & 3;
    const int row = b0 + wr2 * 16 + (L2 >> 4) * 4 + i2;
    const int col = kg * 16 + (L2 & 15);
    float v = 0.f;
#pragma unroll
    for (int q = 0; q < 4; ++q)
        v += smem[((wr2 * 4 + q) * 4 + i2) * 64 + L2];
    T[(size_t)row * H_ + col] = v;
    float cs = v, cs2 = v * v;
    cs  += __shfl_xor(cs, 16);  cs  += __shfl_xor(cs, 32);
    cs2 += __shfl_xor(cs2, 16); cs2 += __shfl_xor(cs2, 32);
    if (L2 < 16) { atomicAdd(&smem[4096 + L2], cs); atomicAdd(&smem[4112 + L2], cs2); }
    __syncthreads();
    if (t < 16)      atomicAdd(&stats[kg * 16 + t],            smem[4096 + t]);
    else if (t < 32) atomicAdd(&stats[128 + kg * 16 + t - 16], smem[4096 + t]);
}

// ---------------------------------------------------------------------------
// Y = (1/8) sum_r BN_r(T_r); ystats. Grid 64 x 256.
__global__ __launch_bounds__(256)
void k_y(const float* __restrict__ T, const float* __restrict__ sums,
         const float* __restrict__ gz, const float* __restrict__ bz,
         float* __restrict__ Y, float* __restrict__ ysums) {
    __shared__ float al[1024], be[1024], red[256];
    const int bx = blockIdx.x, t = threadIdx.x;
    for (int e = t; e < 1024; e += 256) {
        const int rr = e >> 7, k = e & 127;
        const float s1 = sums[rr * 256 + k], s2 = sums[rr * 256 + 128 + k];
        const float mm = s1 * (1.f / B_);
        const float var = s2 * (1.f / B_) - mm * mm;
        const float a = rsqrtf(var + EPS_) * gz[k];
        al[e] = a; be[e] = bz[k] - mm * a;
    }
    red[t] = 0.f;
    __syncthreads();
    const int col = t & 127, half = t >> 7;
    float ps = 0.f, ps2 = 0.f;
    for (int i = 0; i < 16; ++i) {
        const int b = bx * 32 + half + 2 * i;
        float y = 0.f;
#pragma unroll
        for (int rr = 0; rr < 8; ++rr)
            y += fmaf(T[(size_t)rr * B_ * H_ + (size_t)b * H_ + col],
                      al[rr * 128 + col], be[rr * 128 + col]);
        y *= (1.f / RANK_);
        Y[(size_t)b * H_ + col] = y;
        ps += y; ps2 += y * y;
    }
    atomicAdd(&red[col],       half == 0 ? ps  : 0.f);
    atomicAdd(&red[128 + col], half == 0 ? ps2 : 0.f);
    __syncthreads();
    atomicAdd(&red[col],       half == 1 ? ps  : 0.f);
    atomicAdd(&red[128 + col], half == 1 ? ps2 : 0.f);
    __syncthreads();
    if (t < 128) {
        atomicAdd(&ysums[t],       red[t]);
        atomicAdd(&ysums[128 + t], red[128 + t]);
    }
}

// ---------------------------------------------------------------------------
// out = relu(relu(BN(Y)@W3 + b3) + R2). Grid 256 x 256, 8 rows per block.
__global__ __launch_bounds__(256)
void k_out(const float* __restrict__ Y, const float* __restrict__ ystats,
           const float* __restrict__ gy, const float* __restrict__ by,
           const float* __restrict__ W3, const float* __restrict__ b3,
           const float* __restrict__ R2, float* __restrict__ out) {
    __shared__ float sy[8 * 132];
    const int bx = blockIdx.x, t = threadIdx.x;
    const int col = t & 127, rh = t >> 7;
    const int b0 = bx * 8;
    const float mm = ystats[col] * (1.f / B_);
    const float var = ystats[128 + col] * (1.f / B_) - mm * mm;
    const float ay = rsqrtf(var + EPS_) * gy[col];
    const float bb = by[col] - mm * ay;
#pragma unroll
    for (int i = 0; i < 4; ++i) {
        const int row = rh + 2 * i;
        sy[row * 132 + col] = fmaf(Y[(size_t)(b0 + row) * H_ + col], ay, bb);
    }
    __syncthreads();
#pragma unroll
    for (int j = 0; j < 4; ++j) {
        const int row = rh * 4 + j;
        float s = 0.f;
        const float* syr = sy + row * 132;
#pragma unroll 8
        for (int h = 0; h < H_; ++h)
            s = fmaf(syr[h], W3[h * H_ + col], s);
        const size_t gi = (size_t)(b0 + row) * H_ + col;
        out[gi] = fmaxf(fmaxf(s + b3[col], 0.f) + R2[gi], 0.f);
    }
}

// ---------------------------------------------------------------------------
extern "C" void kernel_launch(void* const* d_in, const int* in_sizes, int n_in,
                              void* d_out, int out_size, void* d_ws, size_t ws_size,
                              hipStream_t stream) {
    const float* X  = (const float*)d_in[0];
    const float* W1 = (const float*)d_in[1];
    const float* b1 = (const float*)d_in[2];
    const float* W2 = (const float*)d_in[3];
    const float* b2 = (const float*)d_in[4];
    const float* W3 = (const float*)d_in[5];
    const float* b3 = (const float*)d_in[6];
    const float* P  = (const float*)d_in[7];
    const float* gz = (const float*)d_in[8];
    const float* bz = (const float*)d_in[9];
    const float* gy = (const float*)d_in[10];
    const float* by = (const float*)d_in[11];
    float* out = (float*)d_out;

    const size_t rankElems = (size_t)H_ * H_ * H_;

    char* wsb = (char*)d_ws;
    float* Z      = (float*)wsb;   wsb += (size_t)B_ * H_ * 4;
    float* R2     = (float*)wsb;   wsb += (size_t)B_ * H_ * 4;
    float* Y      = (float*)wsb;   wsb += (size_t)B_ * H_ * 4;
    float* stats  = (float*)wsb;   wsb += (size_t)(RANK_ + 1) * 256 * 4;  // sums | ysums
    float* T      = (float*)wsb;   wsb += (size_t)RANK_ * B_ * H_ * 4;
    __bf16* Zbf   = (__bf16*)wsb;  wsb += (size_t)B_ * H_ * 2;
    __bf16* Pperm = (__bf16*)wsb;

    float* ysums = stats + RANK_ * 256;

    k_head<<<1024, 256, 0, stream>>>(X, W1, b1, W2, b2, P, Z, R2, Zbf, Pperm, stats);

    for (int r = 0; r < RANK_; ++r) {
        const float* prevT = (r == 0) ? Z : (T + (size_t)(r - 1) * B_ * H_);
        const float* prevS = (r == 0) ? stats : (stats + (r - 1) * 256);
        k_rank<<<dim3(8, 32), 1024, 0, stream>>>(Pperm + (size_t)r * rankElems, Zbf,
                                                 prevT, prevS, gz, bz,
                                                 T + (size_t)r * B_ * H_, stats + r * 256,
                                                 r == 0 ? 1 : 0);
    }

    k_y<<<64, 256, 0, stream>>>(T, stats, gz, bz, Y, ysums);
    k_out<<<256, 256, 0, stream>>>(Y, ysums, gy, by, W3, b3, R2, out);
}

// Round 9
// 303.150 us; speedup vs baseline: 1.1791x; 1.1791x over previous
//
#include <hip/hip_runtime.h>

typedef __bf16 bf16x8 __attribute__((ext_vector_type(8)));
typedef float  floatx4 __attribute__((ext_vector_type(4)));

constexpr int B_    = 2048;
constexpr int NIN   = 256;
constexpr int H_    = 128;
constexpr int RANK_ = 8;
constexpr float EPS_ = 1e-5f;

// ---------------------------------------------------------------------------
// HEAD: zero stats; in_proj (2 rows/block); pconv via fp32 LDS transpose
// (stride 129: conflict-free frag reads). Pperm layout: per rank, per kg the
// 512KB slice is CONTIGUOUS: elem ((((g*128+p)*4+s)*64+L)*8+j). Grid 1024x256.
__global__ __launch_bounds__(256)
void k_head(const float* __restrict__ X,
            const float* __restrict__ W1, const float* __restrict__ b1,
            const float* __restrict__ W2, const float* __restrict__ b2,
            const float* __restrict__ P,
            float* __restrict__ Z, float* __restrict__ R2, __bf16* __restrict__ Zbf,
            __bf16* __restrict__ Pperm, float* __restrict__ stats /* 9*256 */) {
    __shared__ float sT[32 * 129];           // 16512 B; reused as sx[512] first
    const int bx = blockIdx.x, t = threadIdx.x;

    if (bx < RANK_ + 1) stats[bx * 256 + t] = 0.f;

    {   // in_proj rows bx*2, bx*2+1
        const int row0 = bx * 2;
        sT[t]       = X[(size_t)row0       * NIN + t];
        sT[256 + t] = X[(size_t)(row0 + 1) * NIN + t];
        __syncthreads();
        const int col = t & 127, half = t >> 7;
        float s1 = 0.f, s2 = 0.f;
        const float* sxh = sT + half * 256;
#pragma unroll 8
        for (int i = 0; i < NIN; ++i) {
            s1 = fmaf(sxh[i], W1[i * H_ + col], s1);
            s2 = fmaf(sxh[i], W2[i * H_ + col], s2);
        }
        const int b = row0 + half;
        const float z = fmaxf(s1 + b1[col], 0.f);
        const float r = fmaxf(s2 + b2[col], 0.f);
        Z[(size_t)b * H_ + col]   = z;
        Zbf[(size_t)b * H_ + col] = (__bf16)z;
        R2[(size_t)b * H_ + col]  = r;
        __syncthreads();
    }
    {   // pconv: unit = bx -> (rank r, p)
        const int r = bx >> 7, p = bx & 127;
        const float4* Pp4 = (const float4*)(P + ((size_t)r * H_ + p) * (H_ * H_));
        __bf16* dst = Pperm + (size_t)r * (H_ * H_ * H_);
        const int L = t & 63, quad = L >> 4, lo = L & 15, g0 = t >> 6;
#pragma unroll
        for (int s = 0; s < 4; ++s) {
#pragma unroll
            for (int it = 0; it < 4; ++it) {     // 32 q-rows x 128 k, coalesced
                const int idx = it * 256 + t;
                const int q = idx >> 5, k4 = idx & 31;
                const float4 v = Pp4[(size_t)(s * 32 + q) * 32 + k4];
                float* d = sT + q * 129 + k4 * 4;
                d[0] = v.x; d[1] = v.y; d[2] = v.z; d[3] = v.w;
            }
            __syncthreads();
#pragma unroll
            for (int gg = 0; gg < 2; ++gg) {     // conflict-free reads, cvt, emit
                const int g = g0 + 4 * gg;
                __bf16 v8[8];
#pragma unroll
                for (int j = 0; j < 8; ++j)
                    v8[j] = (__bf16)sT[(quad * 8 + j) * 129 + g * 16 + lo];
                *(bf16x8*)(dst + (((size_t)(g * 128 + p) * 4 + s) * 64 + L) * 8) =
                    *(const bf16x8*)v8;
            }
            __syncthreads();
        }
    }
}

// ---------------------------------------------------------------------------
// RANK r: T_r = sum_p BNprev(prevT)[:,p] * (Zbf @ P_r[p]); stats_r.
// Grid (8 kg, 32 m) -> XCD = kg; 512 thr (8 waves), 1 block/CU.
// Wave w owns p in [w*16, w*16+16) and ALL 4 m-tiles (64 rows): every B-frag
// read exactly once per block (512KB contiguous slice, L2-resident per XCD).
__global__ __launch_bounds__(512, 2)
void k_rank(const __bf16* __restrict__ Pr, const __bf16* __restrict__ Zbf,
            const float* __restrict__ prevT, const float* __restrict__ prevStats,
            const float* __restrict__ gz, const float* __restrict__ bz,
            float* __restrict__ T, float* __restrict__ stats, const int first) {
    __shared__ float smem[8960];     // sZin[128][68] (=8704) | reduce 8x1024 + cs; sAl/sBe tail
    const int kg = blockIdx.x, mblk = blockIdx.y, b0 = mblk * 64;
    const int t = threadIdx.x;
    const int w = t >> 6, L = t & 63, quad = L >> 4, lo = L & 15;

    float* sAl = smem + 8704; float* sBe = smem + 8832;
    if (t < 128) {
        if (first) { sAl[t] = 1.f; sBe[t] = 0.f; }
        else {
            const float s1 = prevStats[t], s2 = prevStats[128 + t];
            const float mm = s1 * (1.f / B_);
            const float var = s2 * (1.f / B_) - mm * mm;
            const float a = rsqrtf(var + EPS_) * gz[t];
            sAl[t] = a; sBe[t] = bz[t] - mm * a;
        }
    }
    // A-frags: 64 rows x K=128, rank-invariant (64 VGPRs)
    bf16x8 A[4][4];
#pragma unroll
    for (int mt = 0; mt < 4; ++mt)
#pragma unroll
        for (int ks = 0; ks < 4; ++ks)
            A[mt][ks] = *(const bf16x8*)(Zbf + (size_t)(b0 + mt * 16 + lo) * H_ + ks * 32 + quad * 8);
    __syncthreads();
    {   // stage normalized Zin -> sZin[p][row] (stride 68)
        const int sp = t & 127, rr = t >> 7;     // col, row-quarter
        const float a = sAl[sp], be = sBe[sp];
#pragma unroll
        for (int i = 0; i < 16; ++i) {
            const int row = rr + 4 * i;
            smem[sp * 68 + row] = fmaf(prevT[(size_t)(b0 + row) * H_ + sp], a, be);
        }
    }
    __syncthreads();

    floatx4 acc[4];
#pragma unroll
    for (int mt = 0; mt < 4; ++mt) acc[mt] = (floatx4){0.f, 0.f, 0.f, 0.f};

    const bf16x8* Pb = (const bf16x8*)Pr;
    const int p0 = w * 16;
    const size_t fbase = ((size_t)kg * 128 + p0) * 4;   // frag-group base for this wave
    bf16x8 Bf[4], Bn[4];
#pragma unroll
    for (int s = 0; s < 4; ++s) Bf[s] = Pb[(fbase + s) * 64 + L];

    for (int pp = 0; pp < 16; ++pp) {
        const int p = p0 + pp;
        if (pp < 15) {
#pragma unroll
            for (int s = 0; s < 4; ++s)
                Bn[s] = Pb[(fbase + (size_t)(pp + 1) * 4 + s) * 64 + L];
        }
        floatx4 S[4];
#pragma unroll
        for (int mt = 0; mt < 4; ++mt) S[mt] = (floatx4){0.f, 0.f, 0.f, 0.f};
#pragma unroll
        for (int ks = 0; ks < 4; ++ks)
#pragma unroll
            for (int mt = 0; mt < 4; ++mt)
                S[mt] = __builtin_amdgcn_mfma_f32_16x16x32_bf16(A[mt][ks], Bf[ks], S[mt], 0, 0, 0);
#pragma unroll
        for (int mt = 0; mt < 4; ++mt) {
            const floatx4 zi = *(const floatx4*)&smem[p * 68 + mt * 16 + quad * 4];
            acc[mt] += zi * S[mt];
        }
#pragma unroll
        for (int s = 0; s < 4; ++s) Bf[s] = Bn[s];
    }
    __syncthreads();                 // sZin dead; reuse for cross-wave p-reduce
#pragma unroll
    for (int mt = 0; mt < 4; ++mt)
#pragma unroll
        for (int i = 0; i < 4; ++i)
            smem[w * 1024 + (mt * 4 + i) * 64 + L] = acc[mt][i];
    if (t < 32) smem[8192 + t] = 0.f;
    __syncthreads();

    float cs = 0.f, cs2 = 0.f;
#pragma unroll
    for (int k2 = 0; k2 < 2; ++k2) {
        const int e = t + 512 * k2;
        float v = 0.f;
#pragma unroll
        for (int q = 0; q < 8; ++q) v += smem[q * 1024 + e];
        const int j = e >> 6, L2 = e & 63;
        const int row = b0 + (j >> 2) * 16 + (L2 >> 4) * 4 + (j & 3);
        const int col = kg * 16 + (L2 & 15);
        T[(size_t)row * H_ + col] = v;
        cs += v; cs2 += v * v;
    }
    cs  += __shfl_xor(cs, 16);  cs  += __shfl_xor(cs, 32);
    cs2 += __shfl_xor(cs2, 16); cs2 += __shfl_xor(cs2, 32);
    if (L < 16) { atomicAdd(&smem[8192 + L], cs); atomicAdd(&smem[8208 + L], cs2); }
    __syncthreads();
    if (t < 16)      atomicAdd(&stats[kg * 16 + t],            smem[8192 + t]);
    else if (t < 32) atomicAdd(&stats[128 + kg * 16 + t - 16], smem[8192 + t]);
}

// ---------------------------------------------------------------------------
// Y = (1/8) sum_r BN_r(T_r); ystats. Grid 64 x 256.
__global__ __launch_bounds__(256)
void k_y(const float* __restrict__ T, const float* __restrict__ sums,
         const float* __restrict__ gz, const float* __restrict__ bz,
         float* __restrict__ Y, float* __restrict__ ysums) {
    __shared__ float al[1024], be[1024], red[256];
    const int bx = blockIdx.x, t = threadIdx.x;
    for (int e = t; e < 1024; e += 256) {
        const int rr = e >> 7, k = e & 127;
        const float s1 = sums[rr * 256 + k], s2 = sums[rr * 256 + 128 + k];
        const float mm = s1 * (1.f / B_);
        const float var = s2 * (1.f / B_) - mm * mm;
        const float a = rsqrtf(var + EPS_) * gz[k];
        al[e] = a; be[e] = bz[k] - mm * a;
    }
    red[t] = 0.f;
    __syncthreads();
    const int col = t & 127, half = t >> 7;
    float ps = 0.f, ps2 = 0.f;
    for (int i = 0; i < 16; ++i) {
        const int b = bx * 32 + half + 2 * i;
        float y = 0.f;
#pragma unroll
        for (int rr = 0; rr < 8; ++rr)
            y += fmaf(T[(size_t)rr * B_ * H_ + (size_t)b * H_ + col],
                      al[rr * 128 + col], be[rr * 128 + col]);
        y *= (1.f / RANK_);
        Y[(size_t)b * H_ + col] = y;
        ps += y; ps2 += y * y;
    }
    atomicAdd(&red[col],       half == 0 ? ps  : 0.f);
    atomicAdd(&red[128 + col], half == 0 ? ps2 : 0.f);
    __syncthreads();
    atomicAdd(&red[col],       half == 1 ? ps  : 0.f);
    atomicAdd(&red[128 + col], half == 1 ? ps2 : 0.f);
    __syncthreads();
    if (t < 128) {
        atomicAdd(&ysums[t],       red[t]);
        atomicAdd(&ysums[128 + t], red[128 + t]);
    }
}

// ---------------------------------------------------------------------------
// out = relu(relu(BN(Y)@W3 + b3) + R2). Grid 256 x 256, 8 rows per block.
__global__ __launch_bounds__(256)
void k_out(const float* __restrict__ Y, const float* __restrict__ ystats,
           const float* __restrict__ gy, const float* __restrict__ by,
           const float* __restrict__ W3, const float* __restrict__ b3,
           const float* __restrict__ R2, float* __restrict__ out) {
    __shared__ float sy[8 * 132];
    const int bx = blockIdx.x, t = threadIdx.x;
    const int col = t & 127, rh = t >> 7;
    const int b0 = bx * 8;
    const float mm = ystats[col] * (1.f / B_);
    const float var = ystats[128 + col] * (1.f / B_) - mm * mm;
    const float ay = rsqrtf(var + EPS_) * gy[col];
    const float bb = by[col] - mm * ay;
#pragma unroll
    for (int i = 0; i < 4; ++i) {
        const int row = rh + 2 * i;
        sy[row * 132 + col] = fmaf(Y[(size_t)(b0 + row) * H_ + col], ay, bb);
    }
    __syncthreads();
#pragma unroll
    for (int j = 0; j < 4; ++j) {
        const int row = rh * 4 + j;
        float s = 0.f;
        const float* syr = sy + row * 132;
#pragma unroll 8
        for (int h = 0; h < H_; ++h)
            s = fmaf(syr[h], W3[h * H_ + col], s);
        const size_t gi = (size_t)(b0 + row) * H_ + col;
        out[gi] = fmaxf(fmaxf(s + b3[col], 0.f) + R2[gi], 0.f);
    }
}

// ---------------------------------------------------------------------------
extern "C" void kernel_launch(void* const* d_in, const int* in_sizes, int n_in,
                              void* d_out, int out_size, void* d_ws, size_t ws_size,
                              hipStream_t stream) {
    const float* X  = (const float*)d_in[0];
    const float* W1 = (const float*)d_in[1];
    const float* b1 = (const float*)d_in[2];
    const float* W2 = (const float*)d_in[3];
    const float* b2 = (const float*)d_in[4];
    const float* W3 = (const float*)d_in[5];
    const float* b3 = (const float*)d_in[6];
    const float* P  = (const float*)d_in[7];
    const float* gz = (const float*)d_in[8];
    const float* bz = (const float*)d_in[9];
    const float* gy = (const float*)d_in[10];
    const float* by = (const float*)d_in[11];
    float* out = (float*)d_out;

    const size_t rankElems = (size_t)H_ * H_ * H_;

    char* wsb = (char*)d_ws;
    float* Z      = (float*)wsb;   wsb += (size_t)B_ * H_ * 4;
    float* R2     = (float*)wsb;   wsb += (size_t)B_ * H_ * 4;
    float* Y      = (float*)wsb;   wsb += (size_t)B_ * H_ * 4;
    float* stats  = (float*)wsb;   wsb += (size_t)(RANK_ + 1) * 256 * 4;  // sums | ysums
    float* T      = (float*)wsb;   wsb += (size_t)RANK_ * B_ * H_ * 4;
    __bf16* Zbf   = (__bf16*)wsb;  wsb += (size_t)B_ * H_ * 2;
    __bf16* Pperm = (__bf16*)wsb;

    float* ysums = stats + RANK_ * 256;

    k_head<<<1024, 256, 0, stream>>>(X, W1, b1, W2, b2, P, Z, R2, Zbf, Pperm, stats);

    for (int r = 0; r < RANK_; ++r) {
        const float* prevT = (r == 0) ? Z : (T + (size_t)(r - 1) * B_ * H_);
        const float* prevS = (r == 0) ? stats : (stats + (r - 1) * 256);
        k_rank<<<dim3(8, 32), 512, 0, stream>>>(Pperm + (size_t)r * rankElems, Zbf,
                                                prevT, prevS, gz, bz,
                                                T + (size_t)r * B_ * H_, stats + r * 256,
                                                r == 0 ? 1 : 0);
    }

    k_y<<<64, 256, 0, stream>>>(T, stats, gz, bz, Y, ysums);
    k_out<<<256, 256, 0, stream>>>(Y, ysums, gy, by, W3, b3, R2, out);
}